// Round 7
// baseline (195.606 us; speedup 1.0000x reference)
//
#include <hip/hip_runtime.h>

typedef __bf16 bf16x8 __attribute__((ext_vector_type(8)));
typedef float f32x4 __attribute__((ext_vector_type(4)));
typedef int i32x8 __attribute__((ext_vector_type(8)));

// ---------------------------------------------------------------------------
// Problem constants: B=2, C=512, H=W=64 -> N=4096, 32 groups (16 ch/group)
// R7: S+softmax rewritten as swapped-operand St = K.Q^T so each lane owns
// 4-consecutive-j quads -> packed cvt_pk + LDS repack + coalesced dwordx4
// P stores (replaces 64 scattered global byte-stores + 128 shuffles/thread
// that made R6's epilogue 42% VALUBusy). P8 global layout unchanged.
// ---------------------------------------------------------------------------

#if defined(__has_builtin)
#if __has_builtin(__builtin_amdgcn_global_load_lds)
#define HAS_GLL 1
#endif
#endif

__device__ __forceinline__ void async_copy16(const void* g, void* l) {
#ifdef HAS_GLL
    __builtin_amdgcn_global_load_lds(
        (const __attribute__((address_space(1))) unsigned int*)g,
        (__attribute__((address_space(3))) unsigned int*)l, 16, 0, 0);
#else
    *(int4*)l = *(const int4*)g;
#endif
}

__device__ __forceinline__ unsigned char to_fp8(float v) {
    return (unsigned char)(__builtin_amdgcn_cvt_pk_fp8_f32(v, v, 0, false) & 0xFF);
}

#define MXSCALE 0x7F7F7F7F  // e8m0 1.0 in every byte

#define ASM_VMCNT(N) asm volatile("s_waitcnt vmcnt(" #N ")" ::: "memory")
#define ASM_LGKM0() asm volatile("s_waitcnt lgkmcnt(0)" ::: "memory")

// --- Merged: GroupNorm channel partial sums (blocks 0..1023) +
//             weight cast fp32->fp8/bf16 (blocks 1024..2047) ----------------
__global__ __launch_bounds__(256) void prep_kernel(
    const float* __restrict__ x, float* __restrict__ ps,
    const float* __restrict__ wq, const float* __restrict__ wk,
    const float* __restrict__ wv, const float* __restrict__ wp,
    const float* __restrict__ bq, const float* __restrict__ bk,
    unsigned char* __restrict__ wqk8, unsigned char* __restrict__ wv8,
    __bf16* __restrict__ wp_b, float* __restrict__ bqk) {
    if (blockIdx.x >= 1024) {
        int idx = (blockIdx.x - 1024) * 256 + threadIdx.x;  // 262144 = 512*512
        wqk8[idx] = to_fp8(wq[idx]);
        wqk8[262144 + idx] = to_fp8(wk[idx]);
        wv8[idx] = to_fp8(wv[idx]);
        wp_b[idx] = (__bf16)wp[idx];
        if (idx < 512) {
            bqk[idx] = bq[idx];
            bqk[512 + idx] = bk[idx];
        }
        return;
    }
    int blk = blockIdx.x;  // one (b,c) channel: 4096 floats
    const float4* base = (const float4*)x + (size_t)blk * 1024;
    float s1 = 0.f, s2 = 0.f;
#pragma unroll
    for (int i = 0; i < 4; ++i) {
        float4 v = base[threadIdx.x + (i << 8)];
        s1 += v.x + v.y + v.z + v.w;
        s2 += v.x * v.x + v.y * v.y + v.z * v.z + v.w * v.w;
    }
    for (int off = 32; off >= 1; off >>= 1) {
        s1 += __shfl_xor(s1, off);
        s2 += __shfl_xor(s2, off);
    }
    __shared__ float r1[4], r2[4];
    int wave = threadIdx.x >> 6, lane = threadIdx.x & 63;
    if (lane == 0) { r1[wave] = s1; r2[wave] = s2; }
    __syncthreads();
    if (threadIdx.x == 0) {
        ps[blk] = r1[0] + r1[1] + r1[2] + r1[3];
        ps[1024 + blk] = r2[0] + r2[1] + r2[2] + r2[3];
    }
}

// -- GroupNorm finalize + apply + transpose: x[b][c][n] -> hn8[b][n][c] fp8 --
__global__ __launch_bounds__(256) void gn_apply_kernel(const float* __restrict__ x,
                                                       const float* __restrict__ gn_scale,
                                                       const float* __restrict__ gn_bias,
                                                       const float* __restrict__ ps,
                                                       unsigned char* __restrict__ hn8) {
    __shared__ float tile[32][33];
    int b = blockIdx.z;
    int n0 = blockIdx.x * 32, c0 = blockIdx.y * 32;
    int tx = threadIdx.x & 31, ty = threadIdx.x >> 5;  // ty in 0..7
    const float* xb = x + (size_t)b * 512 * 4096;
#pragma unroll
    for (int r = 0; r < 4; ++r) {
        int c = ty + r * 8;
        tile[c][tx] = xb[(size_t)(c0 + c) * 4096 + n0 + tx];
    }
    int c = c0 + tx;
    int g = (b << 5) + (c >> 4);
    float s1 = 0.f, s2 = 0.f;
#pragma unroll
    for (int i = 0; i < 16; ++i) {
        s1 += ps[(g << 4) + i];
        s2 += ps[1024 + (g << 4) + i];
    }
    float m = s1 * (1.f / 65536.f);
    float var = s2 * (1.f / 65536.f) - m * m;
    float rs = rsqrtf(var + 1e-6f);
    float sc = gn_scale[c] * rs;
    float bi = gn_bias[c] - m * sc;
    __syncthreads();
    unsigned char* outp = hn8 + (size_t)b * 4096 * 512;
#pragma unroll
    for (int r = 0; r < 4; ++r) {
        int n = ty + r * 8;
        float v = tile[tx][n];
        outp[(size_t)(n0 + n) * 512 + c] = to_fp8(v * sc + bi);
    }
}

// ---------------------------------------------------------------------------
// Generic MX fp8 GEMM body — counted-vmcnt 2-deep pipeline (T3+T4+T5).
// Used by qkv. OUT: 0=fp8, 1=fp16, 2=bf16. BIAS: 0=none, 1=row, 2=col.
// ---------------------------------------------------------------------------
template <int BN, int OUT_MODE, int BIAS_MODE>
__device__ __forceinline__ void mx_gemm_body(
    const unsigned char* __restrict__ Ab, int lda,
    const unsigned char* __restrict__ Bb, int ldb,
    void* __restrict__ C, int ldc,
    const float* __restrict__ bias, int K, float scale,
    long m0, long n0, unsigned char* As, unsigned char* Bs) {
    constexpr int NT = BN / 32;    // 4 or 2
    constexpr int BSZ = BN * 128;  // bytes per B buffer
    const int tid = threadIdx.x;
    const int lane = tid & 63, wave = tid >> 6;
    const int ln = lane & 15, q = lane >> 4;
    const int wm = (wave >> 1) << 6;
    const int wn = (wave & 1) * (BN / 2);

    f32x4 acc[4][NT] = {};

    auto stage = [&](int kt, int buf) {
        const int k0 = kt << 7;
        unsigned char* Ad = As + buf * 16384;
        unsigned char* Bd = Bs + buf * BSZ;
#pragma unroll
        for (int p = 0; p < 4; ++p) {
            int c = (p << 8) + tid;  // A: 1024 chunks of 16B
            int row = c >> 3, sg = ((c & 7) ^ (row & 7)) << 4;
            async_copy16(Ab + (long)row * lda + k0 + sg, Ad + (c << 4));
        }
#pragma unroll
        for (int p = 0; p < NT; ++p) {
            int c = (p << 8) + tid;
            int row = c >> 3, sg = ((c & 7) ^ (row & 7)) << 4;
            async_copy16(Bb + (long)row * ldb + k0 + sg, Bd + (c << 4));
        }
    };

    const int nk = K >> 7;
    stage(0, 0);
    if (nk > 1) stage(1, 1);

    for (int ki = 0; ki < nk; ++ki) {
        if (ki < nk - 1) {
            if constexpr (NT == 4) ASM_VMCNT(8);
            else ASM_VMCNT(6);
        } else {
            ASM_VMCNT(0);
        }
        __builtin_amdgcn_s_barrier();
        const int cur = ki & 1;
        const unsigned char* Ar = As + cur * 16384;
        const unsigned char* Br = Bs + cur * BSZ;
        i32x8 af[4], bf[NT];
#pragma unroll
        for (int t = 0; t < 4; ++t) {
            int row = wm + t * 16 + ln, e = row & 7;
            const unsigned char* ap = Ar + (row << 7);
            *(int4*)&af[t] = *(const int4*)(ap + ((((q << 1)) ^ e) << 4));
            *((int4*)&af[t] + 1) = *(const int4*)(ap + ((((q << 1) | 1) ^ e) << 4));
        }
#pragma unroll
        for (int t = 0; t < NT; ++t) {
            int row = wn + t * 16 + ln, e = row & 7;
            const unsigned char* bp = Br + (row << 7);
            *(int4*)&bf[t] = *(const int4*)(bp + ((((q << 1)) ^ e) << 4));
            *((int4*)&bf[t] + 1) = *(const int4*)(bp + ((((q << 1) | 1) ^ e) << 4));
        }
        ASM_LGKM0();
        __builtin_amdgcn_s_barrier();
        if (ki + 2 < nk) stage(ki + 2, cur);
        __builtin_amdgcn_s_setprio(1);
#pragma unroll
        for (int mt = 0; mt < 4; ++mt)
#pragma unroll
            for (int nt = 0; nt < NT; ++nt)
                acc[mt][nt] = __builtin_amdgcn_mfma_scale_f32_16x16x128_f8f6f4(
                    af[mt], bf[nt], acc[mt][nt], 0, 0, 0, MXSCALE, 0, MXSCALE);
        __builtin_amdgcn_s_setprio(0);
    }

#pragma unroll
    for (int mt = 0; mt < 4; ++mt) {
#pragma unroll
        for (int nt = 0; nt < NT; ++nt) {
            long col = n0 + wn + nt * 16 + ln;
#pragma unroll
            for (int r = 0; r < 4; ++r) {
                long row = m0 + wm + mt * 16 + (q << 2) + r;
                float v = acc[mt][nt][r] * scale;
                if (BIAS_MODE == 1) v += bias[row];
                if (BIAS_MODE == 2) v += bias[col];
                long off = row * (long)ldc + col;
                if (OUT_MODE == 0) {
                    ((unsigned char*)C)[off] = to_fp8(v);
                } else if (OUT_MODE == 1) {
                    ((_Float16*)C)[off] = (_Float16)v;
                } else {
                    ((__bf16*)C)[off] = (__bf16)v;
                }
            }
        }
    }
}

// --- Merged q|k + v MX GEMM. Grid (8,32,4): z<2 -> qk batch z; z>=2 -> v. ---
__global__ __launch_bounds__(256) void qkv_kernel(
    const unsigned char* __restrict__ hn8, const unsigned char* __restrict__ wqk8,
    const unsigned char* __restrict__ wv8, const float* __restrict__ bqk,
    const float* __restrict__ bv, unsigned char* __restrict__ qk8,
    unsigned char* __restrict__ v8) {
    __shared__ __align__(16) unsigned char As[2 * 128 * 128];
    __shared__ __align__(16) unsigned char Bs[2 * 128 * 128];
    int z = blockIdx.z;
    if (z < 2) {
        long b = z;
        long m0 = (long)blockIdx.y * 128, n0 = (long)blockIdx.x * 128;
        mx_gemm_body<128, 0, 2>(hn8 + b * 4096 * 512 + m0 * 512, 512,
                                wqk8 + n0 * 512, 512,
                                qk8 + b * 4096 * 1024, 1024,
                                bqk, 512, 1.f, m0, n0, As, Bs);
    } else {
        long b = z - 2;
        int flat = blockIdx.y * 8 + blockIdx.x;
        long m0 = (long)(flat >> 6) * 128, n0 = (long)(flat & 63) * 64;
        mx_gemm_body<64, 0, 1>(wv8 + m0 * 512, 512,
                               hn8 + b * 4096 * 512 + n0 * 512, 512,
                               v8 + b * 512 * 4096, 4096,
                               bv, 512, 1.f, m0, n0, As, Bs);
    }
}

// ---------------------------------------------------------------------------
// S + softmax-partial kernel, SWAPPED OPERANDS: computes St[j][i] = K.Q^T.
// C/D layout then gives lane (q,ln), tile (mt,nt):
//   i (output row) = wn + nt*16 + ln        (N dim -> softmax row)
//   j (col)        = wm + mt*16 + q*4 + r   (M dim -> 4 consecutive j per quad)
// Epilogue: per (mt,nt) pack 4 consecutive-j fp8 via 2 cvt_pk -> one u32 ->
// ds_write_b32 into a 16 KB repack tile (reuses As buf0, dead after K-loop),
// XOR-swizzled (2-way, free). Then 4 ds_read_b128 + 4 coalesced
// global_store_dwordx4 per thread. P8 global layout unchanged (row-major).
// Row stats: 15 in-lane fmax + 2 shfl + 1 LDS exchange (vs 128 shfl before).
// ---------------------------------------------------------------------------
__global__ __launch_bounds__(256) void mx_s_softmax_kernel(
    const unsigned char* __restrict__ QK, unsigned char* __restrict__ P8,
    float* __restrict__ pmaxF, float* __restrict__ psumF, float scale) {
    __shared__ __align__(16) unsigned char As[2 * 128 * 128];
    __shared__ __align__(16) unsigned char Bs[2 * 128 * 128];
    __shared__ float sm_max[2][128], sm_sum[2][128];
    int id = (blockIdx.x & 7) * 256 + (blockIdx.x >> 3);  // bijective over 2048
    int mg = id >> 5;
    long b = mg >> 5;
    int panel = mg & 31;               // j-panel (A operand = K rows)
    long j0 = (long)panel * 128;
    long i0 = (long)(id & 31) * 128;   // q-row panel (B operand = output rows)
    const unsigned char* Ab = QK + b * 4096 * 1024 + j0 * 1024 + 512;  // K half
    const unsigned char* Bb = QK + b * 4096 * 1024 + i0 * 1024;        // Q half

    const int tid = threadIdx.x;
    const int lane = tid & 63, wave = tid >> 6;
    const int ln = lane & 15, q = lane >> 4;
    const int wm = (wave >> 1) << 6;  // j offset
    const int wn = (wave & 1) * 64;   // i offset

    f32x4 acc[4][4] = {};

    auto stage = [&](int kt, int buf) {
        const int k0 = kt << 7;
        unsigned char* Ad = As + buf * 16384;
        unsigned char* Bd = Bs + buf * 16384;
#pragma unroll
        for (int p = 0; p < 4; ++p) {
            int c = (p << 8) + tid;
            int row = c >> 3, sg = ((c & 7) ^ (row & 7)) << 4;
            async_copy16(Ab + (long)row * 1024 + k0 + sg, Ad + (c << 4));
        }
#pragma unroll
        for (int p = 0; p < 4; ++p) {
            int c = (p << 8) + tid;
            int row = c >> 3, sg = ((c & 7) ^ (row & 7)) << 4;
            async_copy16(Bb + (long)row * 1024 + k0 + sg, Bd + (c << 4));
        }
    };

    stage(0, 0);
    stage(1, 1);
    for (int ki = 0; ki < 4; ++ki) {
        if (ki < 3) ASM_VMCNT(8);
        else ASM_VMCNT(0);
        __builtin_amdgcn_s_barrier();
        const int cur = ki & 1;
        const unsigned char* Ar = As + cur * 16384;
        const unsigned char* Br = Bs + cur * 16384;
        i32x8 af[4], bf[4];
#pragma unroll
        for (int t = 0; t < 4; ++t) {
            int row = wm + t * 16 + ln, e = row & 7;
            const unsigned char* ap = Ar + (row << 7);
            *(int4*)&af[t] = *(const int4*)(ap + ((((q << 1)) ^ e) << 4));
            *((int4*)&af[t] + 1) = *(const int4*)(ap + ((((q << 1) | 1) ^ e) << 4));
        }
#pragma unroll
        for (int t = 0; t < 4; ++t) {
            int row = wn + t * 16 + ln, e = row & 7;
            const unsigned char* bp = Br + (row << 7);
            *(int4*)&bf[t] = *(const int4*)(bp + ((((q << 1)) ^ e) << 4));
            *((int4*)&bf[t] + 1) = *(const int4*)(bp + ((((q << 1) | 1) ^ e) << 4));
        }
        ASM_LGKM0();
        __builtin_amdgcn_s_barrier();
        if (ki + 2 < 4) stage(ki + 2, cur);
        __builtin_amdgcn_s_setprio(1);
#pragma unroll
        for (int mt = 0; mt < 4; ++mt)
#pragma unroll
            for (int nt = 0; nt < 4; ++nt)
                acc[mt][nt] = __builtin_amdgcn_mfma_scale_f32_16x16x128_f8f6f4(
                    af[mt], bf[nt], acc[mt][nt], 0, 0, 0, MXSCALE, 0, MXSCALE);
        __builtin_amdgcn_s_setprio(0);
    }

    // ---- epilogue: per-row (i) softmax partials, packed P' stores ----
    const float C_ = scale * 1.4426950408889634f;  // fold scale * log2(e)
#pragma unroll
    for (int mt = 0; mt < 4; ++mt)
#pragma unroll
        for (int nt = 0; nt < 4; ++nt)
#pragma unroll
            for (int r = 0; r < 4; ++r) acc[mt][nt][r] *= C_;

    // per-i max: 16 in-lane (mt,r) + cross-q shfl(16,32) + cross-wave LDS
#pragma unroll
    for (int nt = 0; nt < 4; ++nt) {
        float m = acc[0][nt][0];
#pragma unroll
        for (int mt = 0; mt < 4; ++mt)
#pragma unroll
            for (int r = 0; r < 4; ++r) m = fmaxf(m, acc[mt][nt][r]);
        m = fmaxf(m, __shfl_xor(m, 16));
        m = fmaxf(m, __shfl_xor(m, 32));
        if (lane < 16) sm_max[wave >> 1][wn + nt * 16 + ln] = m;
    }
    __syncthreads();

    unsigned int* rp = (unsigned int*)As;  // 16 KB repack tile (buf0 is dead)
    float mtl[4];
#pragma unroll
    for (int nt = 0; nt < 4; ++nt) {
        const int i = wn + nt * 16 + ln;
        mtl[nt] = ceilf(fmaxf(sm_max[0][i], sm_max[1][i]));
        float s = 0.f;
#pragma unroll
        for (int mt = 0; mt < 4; ++mt) {
            float p0 = exp2f(acc[mt][nt][0] - mtl[nt]);
            float p1 = exp2f(acc[mt][nt][1] - mtl[nt]);
            float p2 = exp2f(acc[mt][nt][2] - mtl[nt]);
            float p3 = exp2f(acc[mt][nt][3] - mtl[nt]);
            s += (p0 + p1) + (p2 + p3);
            int w = __builtin_amdgcn_cvt_pk_fp8_f32(p0, p1, 0, false);
            w = __builtin_amdgcn_cvt_pk_fp8_f32(p2, p3, w, true);
            int jq = ((wave >> 1) << 4) + (mt << 2) + q;  // u32 index 0..31
            rp[i * 32 + (jq ^ ((i & 7) << 2))] = (unsigned int)w;
        }
        s += __shfl_xor(s, 16);
        s += __shfl_xor(s, 32);
        if (lane < 16) sm_sum[wave >> 1][i] = s;
    }
    __syncthreads();  // publishes repack tile + sm_sum

    if (wave < 2 && lane < 16) {  // waves 0/1 cover i 0..63 / 64..127
#pragma unroll
        for (int nt = 0; nt < 4; ++nt) {
            int i = wn + nt * 16 + ln;
            long rowg = b * 4096 + i0 + i;
            pmaxF[rowg * 32 + panel] = mtl[nt];
            psumF[rowg * 32 + panel] = sm_sum[0][i] + sm_sum[1][i];
        }
    }

    // coalesced P' store: thread t owns row i=t>>1, 64-byte half (t&1)
    {
        const int i = tid >> 1, half = tid & 1;
        const unsigned int* rr = rp + i * 32;
        unsigned char* Pw = P8 + b * 4096 * 4096 + (i0 + i) * 4096 + j0 + half * 64;
#pragma unroll
        for (int k = 0; k < 4; ++k) {
            int js = (half * 16 + 4 * k) ^ ((i & 7) << 2);  // 4-aligned swizzle
            *(int4*)(Pw + k * 16) = *(const int4*)(rr + js);
        }
    }
}

// ---------------------------------------------------------------------------
// PV with fused softmax finalize (unchanged from R6 — measured-correct).
// ---------------------------------------------------------------------------
__global__ __launch_bounds__(256) void mx_pv_scaled_kernel(
    const unsigned char* __restrict__ P, const unsigned char* __restrict__ V,
    const float* __restrict__ pmaxF, const float* __restrict__ psumF,
    __bf16* __restrict__ O) {
    __shared__ __align__(16) unsigned char As[2 * 128 * 128];  // 32 KB
    __shared__ __align__(16) unsigned char Bs[2 * 64 * 128];   // 16 KB
    __shared__ __align__(16) unsigned char sb_lds[128 * 32];   // 4 KB
    __shared__ float inv_lds[128];
    const int tid = threadIdx.x;
    const int lane = tid & 63, wave = tid >> 6;
    const int ln = lane & 15, q = lane >> 4;
    const int wm = (wave >> 1) << 6, wn = (wave & 1) << 5;
    const int b = blockIdx.x >> 5;
    const long m0 = (long)(blockIdx.x & 31) * 128;
    const long n0 = (long)blockIdx.y * 64;
    const long rowg0 = (long)b * 4096 + m0;

    if (tid < 128) {
        const float4* pm4 = (const float4*)(pmaxF + (rowg0 + tid) * 32);
        const float4* ps4 = (const float4*)(psumF + (rowg0 + tid) * 32);
        float4 pm[8], ps[8];
#pragma unroll
        for (int i = 0; i < 8; ++i) { pm[i] = pm4[i]; ps[i] = ps4[i]; }
        float g = -1e30f;
#pragma unroll
        for (int i = 0; i < 8; ++i)
            g = fmaxf(g, fmaxf(fmaxf(pm[i].x, pm[i].y), fmaxf(pm[i].z, pm[i].w)));
        float denom = 0.f;
        unsigned int* sbw = (unsigned int*)sb_lds + tid * 8;
#pragma unroll
        for (int i = 0; i < 8; ++i) {
            float d0 = pm[i].x - g, d1 = pm[i].y - g, d2 = pm[i].z - g, d3 = pm[i].w - g;
            denom += ps[i].x * exp2f(d0) + ps[i].y * exp2f(d1) +
                     ps[i].z * exp2f(d2) + ps[i].w * exp2f(d3);
            int b0 = 127 + (int)d0, b1 = 127 + (int)d1, b2 = 127 + (int)d2, b3 = 127 + (int)d3;
            b0 = b0 < 0 ? 0 : b0; b1 = b1 < 0 ? 0 : b1;
            b2 = b2 < 0 ? 0 : b2; b3 = b3 < 0 ? 0 : b3;
            sbw[i] = (unsigned)b0 | ((unsigned)b1 << 8) | ((unsigned)b2 << 16) |
                     ((unsigned)b3 << 24);
        }
        inv_lds[tid] = 1.f / denom;
    }
    __syncthreads();

    const unsigned char* Pb = P + rowg0 * 4096;
    const unsigned char* Vb = V + ((long)b * 512 + n0) * 4096;

    f32x4 acc[4][2] = {};

    auto stage = [&](int kt, int buf) {
        const int k0 = kt << 7;
        unsigned char* Ad = As + buf * 16384;
        unsigned char* Bd = Bs + buf * 8192;
#pragma unroll
        for (int p = 0; p < 4; ++p) {
            int c = (p << 8) + tid;
            int row = c >> 3, sg = ((c & 7) ^ (row & 7)) << 4;
            async_copy16(Pb + (long)row * 4096 + k0 + sg, Ad + (c << 4));
        }
#pragma unroll
        for (int p = 0; p < 2; ++p) {
            int c = (p << 8) + tid;
            int row = c >> 3, sg = ((c & 7) ^ (row & 7)) << 4;
            async_copy16(Vb + (long)row * 4096 + k0 + sg, Bd + (c << 4));
        }
    };

    stage(0, 0);
    stage(1, 1);
    for (int ki = 0; ki < 32; ++ki) {
        if (ki < 31) ASM_VMCNT(6);
        else ASM_VMCNT(0);
        __builtin_amdgcn_s_barrier();
        const int cur = ki & 1;
        const unsigned char* Ar = As + cur * 16384;
        const unsigned char* Br = Bs + cur * 8192;
        i32x8 af[4], bf[2];
        int saw[4];
#pragma unroll
        for (int t = 0; t < 4; ++t) {
            int row = wm + t * 16 + ln, e = row & 7;
            const unsigned char* ap = Ar + (row << 7);
            *(int4*)&af[t] = *(const int4*)(ap + ((((q << 1)) ^ e) << 4));
            *((int4*)&af[t] + 1) = *(const int4*)(ap + ((((q << 1) | 1) ^ e) << 4));
            saw[t] = (int)sb_lds[(row << 5) + ki] * 0x01010101;  // byte in all lanes
        }
#pragma unroll
        for (int t = 0; t < 2; ++t) {
            int row = wn + t * 16 + ln, e = row & 7;
            const unsigned char* bp = Br + (row << 7);
            *(int4*)&bf[t] = *(const int4*)(bp + ((((q << 1)) ^ e) << 4));
            *((int4*)&bf[t] + 1) = *(const int4*)(bp + ((((q << 1) | 1) ^ e) << 4));
        }
        ASM_LGKM0();
        __builtin_amdgcn_s_barrier();
        if (ki + 2 < 32) stage(ki + 2, cur);
        __builtin_amdgcn_s_setprio(1);
#pragma unroll
        for (int mt = 0; mt < 4; ++mt)
#pragma unroll
            for (int nt = 0; nt < 2; ++nt)
                acc[mt][nt] = __builtin_amdgcn_mfma_scale_f32_16x16x128_f8f6f4(
                    af[mt], bf[nt], acc[mt][nt], 0, 0, 0, saw[mt], 0, MXSCALE);
        __builtin_amdgcn_s_setprio(0);
    }

    __bf16* Ob = O + (long)b * 4096 * 512;
#pragma unroll
    for (int mt = 0; mt < 4; ++mt) {
#pragma unroll
        for (int nt = 0; nt < 2; ++nt) {
            long col = n0 + wn + nt * 16 + ln;
#pragma unroll
            for (int r = 0; r < 4; ++r) {
                int rowl = wm + mt * 16 + (q << 2) + r;
                Ob[(m0 + rowl) * 512 + col] = (__bf16)(acc[mt][nt][r] * inv_lds[rowl]);
            }
        }
    }
}

// ---------------------------------------------------------------------------
// Proj GEMM (bf16 anchor): out = wp.o_t + bp + x. Memory-bound.
// ---------------------------------------------------------------------------
__global__ __launch_bounds__(256) void proj_kernel(
    const __bf16* __restrict__ A, const __bf16* __restrict__ Bt, long bsB,
    float* __restrict__ C, long bsC, const float* __restrict__ bias,
    const float* __restrict__ resid) {
    __shared__ __align__(16) __bf16 As[128][64];
    __shared__ __align__(16) __bf16 Bs[64][64];
    const int tid = threadIdx.x;
    const int wave = tid >> 6, lane = tid & 63;
    const int q = lane >> 4, ln = lane & 15;
    const int wm = wave << 5;
    const long m0 = (long)blockIdx.y * 128, n0 = (long)blockIdx.x * 64;
    const int b = blockIdx.z;
    const __bf16* Ab = A + m0 * 512;
    const __bf16* Bb = Bt + (long)b * bsB + n0 * 512;

    f32x4 acc[2][4] = {};

    for (int k0 = 0; k0 < 512; k0 += 64) {
        __syncthreads();
#pragma unroll
        for (int p = 0; p < 4; ++p) {
            int c = (p << 8) + tid;
            int row = c >> 3, sg = (c & 7) << 3;
            async_copy16(Ab + (long)row * 512 + k0 + sg, &As[0][0] + (c << 3));
        }
#pragma unroll
        for (int p = 0; p < 2; ++p) {
            int c = (p << 8) + tid;
            int row = c >> 3, sg = (c & 7) << 3;
            async_copy16(Bb + (long)row * 512 + k0 + sg, &Bs[0][0] + (c << 3));
        }
        __syncthreads();
#pragma unroll
        for (int kk = 0; kk < 2; ++kk) {
            bf16x8 af[2], bfr[4];
#pragma unroll
            for (int mt = 0; mt < 2; ++mt)
                af[mt] = *(const bf16x8*)(&As[wm + mt * 16 + ln][(kk << 5) + (q << 3)]);
#pragma unroll
            for (int nt = 0; nt < 4; ++nt)
                bfr[nt] = *(const bf16x8*)(&Bs[nt * 16 + ln][(kk << 5) + (q << 3)]);
#pragma unroll
            for (int mt = 0; mt < 2; ++mt)
#pragma unroll
                for (int nt = 0; nt < 4; ++nt)
                    acc[mt][nt] = __builtin_amdgcn_mfma_f32_16x16x32_bf16(
                        af[mt], bfr[nt], acc[mt][nt], 0, 0, 0);
        }
    }

#pragma unroll
    for (int mt = 0; mt < 2; ++mt) {
#pragma unroll
        for (int nt = 0; nt < 4; ++nt) {
            long col = n0 + nt * 16 + ln;
#pragma unroll
            for (int r = 0; r < 4; ++r) {
                long row = m0 + wm + mt * 16 + (q << 2) + r;
                long off = (long)b * bsC + row * 4096 + col;
                C[off] = acc[mt][nt][r] + bias[row] + resid[off];
            }
        }
    }
}

// ---------------------------------------------------------------------------
extern "C" void kernel_launch(void* const* d_in, const int* in_sizes, int n_in,
                              void* d_out, int out_size, void* d_ws, size_t ws_size,
                              hipStream_t stream) {
    const float* x = (const float*)d_in[0];
    const float* gn_scale = (const float*)d_in[1];
    const float* gn_bias = (const float*)d_in[2];
    const float* wq = (const float*)d_in[3];
    const float* bq = (const float*)d_in[4];
    const float* wk = (const float*)d_in[5];
    const float* bk = (const float*)d_in[6];
    const float* wv = (const float*)d_in[7];
    const float* bv = (const float*)d_in[8];
    const float* wp = (const float*)d_in[9];
    const float* bp = (const float*)d_in[10];
    float* out = (float*)d_out;

    char* ws = (char*)d_ws;
    unsigned char* wqk8 = (unsigned char*)(ws + 0x0);      // [1024][512] fp8
    unsigned char* wv8 = (unsigned char*)(ws + 0x80000);   // [512][512] fp8
    __bf16* wp_b = (__bf16*)(ws + 0xC0000);                // [512][512] bf16
    float* bqk = (float*)(ws + 0x140000);                  // [1024] f32
    float* psum = (float*)(ws + 0x142000);                 // [2][1024] f32
    unsigned char* hn8 = (unsigned char*)(ws + 0x150000);  // [2][4096][512] fp8, 4 MB
    unsigned char* qk8 = (unsigned char*)(ws + 0x550000);  // [2][4096][1024] fp8, 8 MB
    unsigned char* v8 = (unsigned char*)(ws + 0xD50000);   // [2][512][4096] fp8, 4 MB
    __bf16* o_t = (__bf16*)(ws + 0x1150000);               // [2][4096][512] bf16, 8 MB
    unsigned char* S8 = (unsigned char*)(ws + 0x1950000);  // [2][4096][4096] fp8 P', 32 MB
    float* pmaxF = (float*)(ws + 0x3950000);               // [8192][32] f32, 1 MB
    float* psumF = (float*)(ws + 0x3A50000);               // [8192][32] f32, 1 MB
    (void)ws_size;  // ~61 MB footprint

    prep_kernel<<<2048, 256, 0, stream>>>(x, psum, wq, wk, wv, wp, bq, bk,
                                          wqk8, wv8, wp_b, bqk);
    gn_apply_kernel<<<dim3(128, 16, 2), 256, 0, stream>>>(x, gn_scale, gn_bias,
                                                          psum, hn8);
    qkv_kernel<<<dim3(8, 32, 4), 256, 0, stream>>>(hn8, wqk8, wv8, bqk, bv,
                                                   qk8, v8);

    const float attn_scale = 0.044194173824159216f;  // 512^-0.5
    // St = K.Q^T + per-panel softmax partials (2048 blocks, XCD-chunked)
    mx_s_softmax_kernel<<<2048, 256, 0, stream>>>(qk8, S8, pmaxF, psumF,
                                                  attn_scale);
    // PV with e8m0 row-block scales + 1/denom epilogue (512 blocks)
    mx_pv_scaled_kernel<<<dim3(64, 8), 256, 0, stream>>>(S8, v8, pmaxF, psumF,
                                                         o_t);

    proj_kernel<<<dim3(64, 4, 2), 256, 0, stream>>>(
        wp_b, o_t, 4096l * 512, out, 512l * 4096, bp, x);
}

// Round 8
// 187.098 us; speedup vs baseline: 1.0455x; 1.0455x over previous
//
#include <hip/hip_runtime.h>

typedef __bf16 bf16x8 __attribute__((ext_vector_type(8)));
typedef float f32x4 __attribute__((ext_vector_type(4)));
typedef int i32x8 __attribute__((ext_vector_type(8)));

// ---------------------------------------------------------------------------
// Problem constants: B=2, C=512, H=W=64 -> N=4096, 32 groups (16 ch/group)
// R8: short-K kernels (S, qkv: K=512 -> 4 iters) switch from 2x-LDS
// double-buffer to single-buffered 2-barrier loops. Halved LDS doubles
// blocks/CU (S 66->34 KB = 4/CU; qkv 64->32 KB = 4-5/CU): cross-block TLP
// hides staging latency that a 4-iter pipeline cannot (R7 counters: S at
// 19% occupancy, MfmaUtil 11%, VALUBusy 27%, HBM 14% -> latency-bound).
// PV (32 iters) keeps the counted-vmcnt pipeline. Numerics unchanged.
// ---------------------------------------------------------------------------

#if defined(__has_builtin)
#if __has_builtin(__builtin_amdgcn_global_load_lds)
#define HAS_GLL 1
#endif
#endif

__device__ __forceinline__ void async_copy16(const void* g, void* l) {
#ifdef HAS_GLL
    __builtin_amdgcn_global_load_lds(
        (const __attribute__((address_space(1))) unsigned int*)g,
        (__attribute__((address_space(3))) unsigned int*)l, 16, 0, 0);
#else
    *(int4*)l = *(const int4*)g;
#endif
}

__device__ __forceinline__ unsigned char to_fp8(float v) {
    return (unsigned char)(__builtin_amdgcn_cvt_pk_fp8_f32(v, v, 0, false) & 0xFF);
}

#define MXSCALE 0x7F7F7F7F  // e8m0 1.0 in every byte

#define ASM_VMCNT(N) asm volatile("s_waitcnt vmcnt(" #N ")" ::: "memory")
#define ASM_LGKM0() asm volatile("s_waitcnt lgkmcnt(0)" ::: "memory")

// --- Merged: GroupNorm channel partial sums (blocks 0..1023) +
//             weight cast fp32->fp8/bf16 (blocks 1024..2047) ----------------
__global__ __launch_bounds__(256) void prep_kernel(
    const float* __restrict__ x, float* __restrict__ ps,
    const float* __restrict__ wq, const float* __restrict__ wk,
    const float* __restrict__ wv, const float* __restrict__ wp,
    const float* __restrict__ bq, const float* __restrict__ bk,
    unsigned char* __restrict__ wqk8, unsigned char* __restrict__ wv8,
    __bf16* __restrict__ wp_b, float* __restrict__ bqk) {
    if (blockIdx.x >= 1024) {
        int idx = (blockIdx.x - 1024) * 256 + threadIdx.x;  // 262144 = 512*512
        wqk8[idx] = to_fp8(wq[idx]);
        wqk8[262144 + idx] = to_fp8(wk[idx]);
        wv8[idx] = to_fp8(wv[idx]);
        wp_b[idx] = (__bf16)wp[idx];
        if (idx < 512) {
            bqk[idx] = bq[idx];
            bqk[512 + idx] = bk[idx];
        }
        return;
    }
    int blk = blockIdx.x;  // one (b,c) channel: 4096 floats
    const float4* base = (const float4*)x + (size_t)blk * 1024;
    float s1 = 0.f, s2 = 0.f;
#pragma unroll
    for (int i = 0; i < 4; ++i) {
        float4 v = base[threadIdx.x + (i << 8)];
        s1 += v.x + v.y + v.z + v.w;
        s2 += v.x * v.x + v.y * v.y + v.z * v.z + v.w * v.w;
    }
    for (int off = 32; off >= 1; off >>= 1) {
        s1 += __shfl_xor(s1, off);
        s2 += __shfl_xor(s2, off);
    }
    __shared__ float r1[4], r2[4];
    int wave = threadIdx.x >> 6, lane = threadIdx.x & 63;
    if (lane == 0) { r1[wave] = s1; r2[wave] = s2; }
    __syncthreads();
    if (threadIdx.x == 0) {
        ps[blk] = r1[0] + r1[1] + r1[2] + r1[3];
        ps[1024 + blk] = r2[0] + r2[1] + r2[2] + r2[3];
    }
}

// -- GroupNorm finalize + apply + transpose: x[b][c][n] -> hn8[b][n][c] fp8 --
__global__ __launch_bounds__(256) void gn_apply_kernel(const float* __restrict__ x,
                                                       const float* __restrict__ gn_scale,
                                                       const float* __restrict__ gn_bias,
                                                       const float* __restrict__ ps,
                                                       unsigned char* __restrict__ hn8) {
    __shared__ float tile[32][33];
    int b = blockIdx.z;
    int n0 = blockIdx.x * 32, c0 = blockIdx.y * 32;
    int tx = threadIdx.x & 31, ty = threadIdx.x >> 5;  // ty in 0..7
    const float* xb = x + (size_t)b * 512 * 4096;
#pragma unroll
    for (int r = 0; r < 4; ++r) {
        int c = ty + r * 8;
        tile[c][tx] = xb[(size_t)(c0 + c) * 4096 + n0 + tx];
    }
    int c = c0 + tx;
    int g = (b << 5) + (c >> 4);
    float s1 = 0.f, s2 = 0.f;
#pragma unroll
    for (int i = 0; i < 16; ++i) {
        s1 += ps[(g << 4) + i];
        s2 += ps[1024 + (g << 4) + i];
    }
    float m = s1 * (1.f / 65536.f);
    float var = s2 * (1.f / 65536.f) - m * m;
    float rs = rsqrtf(var + 1e-6f);
    float sc = gn_scale[c] * rs;
    float bi = gn_bias[c] - m * sc;
    __syncthreads();
    unsigned char* outp = hn8 + (size_t)b * 4096 * 512;
#pragma unroll
    for (int r = 0; r < 4; ++r) {
        int n = ty + r * 8;
        float v = tile[tx][n];
        outp[(size_t)(n0 + n) * 512 + c] = to_fp8(v * sc + bi);
    }
}

// ---------------------------------------------------------------------------
// Generic MX fp8 GEMM body — SINGLE-buffered 2-barrier loop (short K).
// Occupancy over pipelining: used by qkv (K=512, 4 iters). LDS = 16+BN/8 KB.
// OUT: 0=fp8, 1=fp16, 2=bf16. BIAS: 0=none, 1=row, 2=col.
// ---------------------------------------------------------------------------
template <int BN, int OUT_MODE, int BIAS_MODE>
__device__ __forceinline__ void mx_gemm_body(
    const unsigned char* __restrict__ Ab, int lda,
    const unsigned char* __restrict__ Bb, int ldb,
    void* __restrict__ C, int ldc,
    const float* __restrict__ bias, int K, float scale,
    long m0, long n0, unsigned char* As, unsigned char* Bs) {
    constexpr int NT = BN / 32;  // 4 or 2
    const int tid = threadIdx.x;
    const int lane = tid & 63, wave = tid >> 6;
    const int ln = lane & 15, q = lane >> 4;
    const int wm = (wave >> 1) << 6;
    const int wn = (wave & 1) * (BN / 2);

    f32x4 acc[4][NT] = {};

    const int nk = K >> 7;
    for (int ki = 0; ki < nk; ++ki) {
        const int k0 = ki << 7;
        __syncthreads();  // all reads of previous tile retired
#pragma unroll
        for (int p = 0; p < 4; ++p) {
            int c = (p << 8) + tid;  // A: 1024 chunks of 16B
            int row = c >> 3, sg = ((c & 7) ^ (row & 7)) << 4;
            async_copy16(Ab + (long)row * lda + k0 + sg, &As[c << 4]);
        }
#pragma unroll
        for (int p = 0; p < NT; ++p) {
            int c = (p << 8) + tid;
            int row = c >> 3, sg = ((c & 7) ^ (row & 7)) << 4;
            async_copy16(Bb + (long)row * ldb + k0 + sg, &Bs[c << 4]);
        }
        __syncthreads();  // drains global_load_lds + publishes
        i32x8 af[4], bf[NT];
#pragma unroll
        for (int t = 0; t < 4; ++t) {
            int row = wm + t * 16 + ln, e = row & 7;
            const unsigned char* ap = &As[row << 7];
            *(int4*)&af[t] = *(const int4*)(ap + ((((q << 1)) ^ e) << 4));
            *((int4*)&af[t] + 1) = *(const int4*)(ap + ((((q << 1) | 1) ^ e) << 4));
        }
#pragma unroll
        for (int t = 0; t < NT; ++t) {
            int row = wn + t * 16 + ln, e = row & 7;
            const unsigned char* bp = &Bs[row << 7];
            *(int4*)&bf[t] = *(const int4*)(bp + ((((q << 1)) ^ e) << 4));
            *((int4*)&bf[t] + 1) = *(const int4*)(bp + ((((q << 1) | 1) ^ e) << 4));
        }
        __builtin_amdgcn_s_setprio(1);
#pragma unroll
        for (int mt = 0; mt < 4; ++mt)
#pragma unroll
            for (int nt = 0; nt < NT; ++nt)
                acc[mt][nt] = __builtin_amdgcn_mfma_scale_f32_16x16x128_f8f6f4(
                    af[mt], bf[nt], acc[mt][nt], 0, 0, 0, MXSCALE, 0, MXSCALE);
        __builtin_amdgcn_s_setprio(0);
    }

#pragma unroll
    for (int mt = 0; mt < 4; ++mt) {
#pragma unroll
        for (int nt = 0; nt < NT; ++nt) {
            long col = n0 + wn + nt * 16 + ln;
#pragma unroll
            for (int r = 0; r < 4; ++r) {
                long row = m0 + wm + mt * 16 + (q << 2) + r;
                float v = acc[mt][nt][r] * scale;
                if (BIAS_MODE == 1) v += bias[row];
                if (BIAS_MODE == 2) v += bias[col];
                long off = row * (long)ldc + col;
                if (OUT_MODE == 0) {
                    ((unsigned char*)C)[off] = to_fp8(v);
                } else if (OUT_MODE == 1) {
                    ((_Float16*)C)[off] = (_Float16)v;
                } else {
                    ((__bf16*)C)[off] = (__bf16)v;
                }
            }
        }
    }
}

// --- Merged q|k + v MX GEMM. Grid (8,32,4): z<2 -> qk batch z; z>=2 -> v. ---
// Single-buffered: 32 KB LDS -> 4-5 blocks/CU (entire 1024-block grid resident).
__global__ __launch_bounds__(256) void qkv_kernel(
    const unsigned char* __restrict__ hn8, const unsigned char* __restrict__ wqk8,
    const unsigned char* __restrict__ wv8, const float* __restrict__ bqk,
    const float* __restrict__ bv, unsigned char* __restrict__ qk8,
    unsigned char* __restrict__ v8) {
    __shared__ __align__(16) unsigned char As[128 * 128];  // 16 KB
    __shared__ __align__(16) unsigned char Bs[128 * 128];  // 16 KB
    int z = blockIdx.z;
    if (z < 2) {
        long b = z;
        long m0 = (long)blockIdx.y * 128, n0 = (long)blockIdx.x * 128;
        mx_gemm_body<128, 0, 2>(hn8 + b * 4096 * 512 + m0 * 512, 512,
                                wqk8 + n0 * 512, 512,
                                qk8 + b * 4096 * 1024, 1024,
                                bqk, 512, 1.f, m0, n0, As, Bs);
    } else {
        long b = z - 2;
        int flat = blockIdx.y * 8 + blockIdx.x;
        long m0 = (long)(flat >> 6) * 128, n0 = (long)(flat & 63) * 64;
        mx_gemm_body<64, 0, 1>(wv8 + m0 * 512, 512,
                               hn8 + b * 4096 * 512 + n0 * 512, 512,
                               v8 + b * 512 * 4096, 4096,
                               bv, 512, 1.f, m0, n0, As, Bs);
    }
}

// ---------------------------------------------------------------------------
// S + softmax-partial kernel, swapped operands (St = K.Q^T), R7 epilogue,
// SINGLE-buffered loop: LDS 34 KB -> 4 blocks/CU (was 66 KB / 2 blocks/CU).
//   i (output row) = wn + nt*16 + ln        (N dim -> softmax row)
//   j (col)        = wm + mt*16 + q*4 + r   (M dim -> 4 consecutive j per quad)
// Epilogue: packed cvt_pk -> LDS repack (As, dead after loop) -> coalesced
// dwordx4 P stores. Row stats via 2 shfl + 1 LDS exchange.
// ---------------------------------------------------------------------------
__global__ __launch_bounds__(256) void mx_s_softmax_kernel(
    const unsigned char* __restrict__ QK, unsigned char* __restrict__ P8,
    float* __restrict__ pmaxF, float* __restrict__ psumF, float scale) {
    __shared__ __align__(16) unsigned char As[128 * 128];  // 16 KB
    __shared__ __align__(16) unsigned char Bs[128 * 128];  // 16 KB
    __shared__ float sm_max[2][128], sm_sum[2][128];
    int id = (blockIdx.x & 7) * 256 + (blockIdx.x >> 3);  // bijective over 2048
    int mg = id >> 5;
    long b = mg >> 5;
    int panel = mg & 31;               // j-panel (A operand = K rows)
    long j0 = (long)panel * 128;
    long i0 = (long)(id & 31) * 128;   // q-row panel (B operand = output rows)
    const unsigned char* Ab = QK + b * 4096 * 1024 + j0 * 1024 + 512;  // K half
    const unsigned char* Bb = QK + b * 4096 * 1024 + i0 * 1024;        // Q half

    const int tid = threadIdx.x;
    const int lane = tid & 63, wave = tid >> 6;
    const int ln = lane & 15, q = lane >> 4;
    const int wm = (wave >> 1) << 6;  // j offset
    const int wn = (wave & 1) * 64;   // i offset

    f32x4 acc[4][4] = {};

    for (int ki = 0; ki < 4; ++ki) {
        const int k0 = ki << 7;
        __syncthreads();
#pragma unroll
        for (int p = 0; p < 4; ++p) {
            int c = (p << 8) + tid;
            int row = c >> 3, sg = ((c & 7) ^ (row & 7)) << 4;
            async_copy16(Ab + (long)row * 1024 + k0 + sg, &As[c << 4]);
        }
#pragma unroll
        for (int p = 0; p < 4; ++p) {
            int c = (p << 8) + tid;
            int row = c >> 3, sg = ((c & 7) ^ (row & 7)) << 4;
            async_copy16(Bb + (long)row * 1024 + k0 + sg, &Bs[c << 4]);
        }
        __syncthreads();
        i32x8 af[4], bf[4];
#pragma unroll
        for (int t = 0; t < 4; ++t) {
            int row = wm + t * 16 + ln, e = row & 7;
            const unsigned char* ap = &As[row << 7];
            *(int4*)&af[t] = *(const int4*)(ap + ((((q << 1)) ^ e) << 4));
            *((int4*)&af[t] + 1) = *(const int4*)(ap + ((((q << 1) | 1) ^ e) << 4));
        }
#pragma unroll
        for (int t = 0; t < 4; ++t) {
            int row = wn + t * 16 + ln, e = row & 7;
            const unsigned char* bp = &Bs[row << 7];
            *(int4*)&bf[t] = *(const int4*)(bp + ((((q << 1)) ^ e) << 4));
            *((int4*)&bf[t] + 1) = *(const int4*)(bp + ((((q << 1) | 1) ^ e) << 4));
        }
        __builtin_amdgcn_s_setprio(1);
#pragma unroll
        for (int mt = 0; mt < 4; ++mt)
#pragma unroll
            for (int nt = 0; nt < 4; ++nt)
                acc[mt][nt] = __builtin_amdgcn_mfma_scale_f32_16x16x128_f8f6f4(
                    af[mt], bf[nt], acc[mt][nt], 0, 0, 0, MXSCALE, 0, MXSCALE);
        __builtin_amdgcn_s_setprio(0);
    }

    // ---- epilogue: per-row (i) softmax partials, packed P' stores ----
    const float C_ = scale * 1.4426950408889634f;  // fold scale * log2(e)
#pragma unroll
    for (int mt = 0; mt < 4; ++mt)
#pragma unroll
        for (int nt = 0; nt < 4; ++nt)
#pragma unroll
            for (int r = 0; r < 4; ++r) acc[mt][nt][r] *= C_;

#pragma unroll
    for (int nt = 0; nt < 4; ++nt) {
        float m = acc[0][nt][0];
#pragma unroll
        for (int mt = 0; mt < 4; ++mt)
#pragma unroll
            for (int r = 0; r < 4; ++r) m = fmaxf(m, acc[mt][nt][r]);
        m = fmaxf(m, __shfl_xor(m, 16));
        m = fmaxf(m, __shfl_xor(m, 32));
        if (lane < 16) sm_max[wave >> 1][wn + nt * 16 + ln] = m;
    }
    __syncthreads();  // also guarantees all ds_reads of As retired

    unsigned int* rp = (unsigned int*)As;  // 16 KB repack tile (As is dead)
    float mtl[4];
#pragma unroll
    for (int nt = 0; nt < 4; ++nt) {
        const int i = wn + nt * 16 + ln;
        mtl[nt] = ceilf(fmaxf(sm_max[0][i], sm_max[1][i]));
        float s = 0.f;
#pragma unroll
        for (int mt = 0; mt < 4; ++mt) {
            float p0 = exp2f(acc[mt][nt][0] - mtl[nt]);
            float p1 = exp2f(acc[mt][nt][1] - mtl[nt]);
            float p2 = exp2f(acc[mt][nt][2] - mtl[nt]);
            float p3 = exp2f(acc[mt][nt][3] - mtl[nt]);
            s += (p0 + p1) + (p2 + p3);
            int w = __builtin_amdgcn_cvt_pk_fp8_f32(p0, p1, 0, false);
            w = __builtin_amdgcn_cvt_pk_fp8_f32(p2, p3, w, true);
            int jq = ((wave >> 1) << 4) + (mt << 2) + q;  // u32 index 0..31
            rp[i * 32 + (jq ^ ((i & 7) << 2))] = (unsigned int)w;
        }
        s += __shfl_xor(s, 16);
        s += __shfl_xor(s, 32);
        if (lane < 16) sm_sum[wave >> 1][i] = s;
    }
    __syncthreads();  // publishes repack tile + sm_sum

    if (wave < 2 && lane < 16) {  // waves 0/1 cover i 0..63 / 64..127
#pragma unroll
        for (int nt = 0; nt < 4; ++nt) {
            int i = wn + nt * 16 + ln;
            long rowg = b * 4096 + i0 + i;
            pmaxF[rowg * 32 + panel] = mtl[nt];
            psumF[rowg * 32 + panel] = sm_sum[0][i] + sm_sum[1][i];
        }
    }

    // coalesced P' store: thread t owns row i=t>>1, 64-byte half (t&1)
    {
        const int i = tid >> 1, half = tid & 1;
        const unsigned int* rr = rp + i * 32;
        unsigned char* Pw = P8 + b * 4096 * 4096 + (i0 + i) * 4096 + j0 + half * 64;
#pragma unroll
        for (int k = 0; k < 4; ++k) {
            int js = (half * 16 + 4 * k) ^ ((i & 7) << 2);  // 4-aligned swizzle
            *(int4*)(Pw + k * 16) = *(const int4*)(rr + js);
        }
    }
}

// ---------------------------------------------------------------------------
// PV with fused softmax finalize (unchanged — counted-vmcnt, 32 iters).
// ---------------------------------------------------------------------------
__global__ __launch_bounds__(256) void mx_pv_scaled_kernel(
    const unsigned char* __restrict__ P, const unsigned char* __restrict__ V,
    const float* __restrict__ pmaxF, const float* __restrict__ psumF,
    __bf16* __restrict__ O) {
    __shared__ __align__(16) unsigned char As[2 * 128 * 128];  // 32 KB
    __shared__ __align__(16) unsigned char Bs[2 * 64 * 128];   // 16 KB
    __shared__ __align__(16) unsigned char sb_lds[128 * 32];   // 4 KB
    __shared__ float inv_lds[128];
    const int tid = threadIdx.x;
    const int lane = tid & 63, wave = tid >> 6;
    const int ln = lane & 15, q = lane >> 4;
    const int wm = (wave >> 1) << 6, wn = (wave & 1) << 5;
    const int b = blockIdx.x >> 5;
    const long m0 = (long)(blockIdx.x & 31) * 128;
    const long n0 = (long)blockIdx.y * 64;
    const long rowg0 = (long)b * 4096 + m0;

    if (tid < 128) {
        const float4* pm4 = (const float4*)(pmaxF + (rowg0 + tid) * 32);
        const float4* ps4 = (const float4*)(psumF + (rowg0 + tid) * 32);
        float4 pm[8], ps[8];
#pragma unroll
        for (int i = 0; i < 8; ++i) { pm[i] = pm4[i]; ps[i] = ps4[i]; }
        float g = -1e30f;
#pragma unroll
        for (int i = 0; i < 8; ++i)
            g = fmaxf(g, fmaxf(fmaxf(pm[i].x, pm[i].y), fmaxf(pm[i].z, pm[i].w)));
        float denom = 0.f;
        unsigned int* sbw = (unsigned int*)sb_lds + tid * 8;
#pragma unroll
        for (int i = 0; i < 8; ++i) {
            float d0 = pm[i].x - g, d1 = pm[i].y - g, d2 = pm[i].z - g, d3 = pm[i].w - g;
            denom += ps[i].x * exp2f(d0) + ps[i].y * exp2f(d1) +
                     ps[i].z * exp2f(d2) + ps[i].w * exp2f(d3);
            int b0 = 127 + (int)d0, b1 = 127 + (int)d1, b2 = 127 + (int)d2, b3 = 127 + (int)d3;
            b0 = b0 < 0 ? 0 : b0; b1 = b1 < 0 ? 0 : b1;
            b2 = b2 < 0 ? 0 : b2; b3 = b3 < 0 ? 0 : b3;
            sbw[i] = (unsigned)b0 | ((unsigned)b1 << 8) | ((unsigned)b2 << 16) |
                     ((unsigned)b3 << 24);
        }
        inv_lds[tid] = 1.f / denom;
    }
    __syncthreads();

    const unsigned char* Pb = P + rowg0 * 4096;
    const unsigned char* Vb = V + ((long)b * 512 + n0) * 4096;

    f32x4 acc[4][2] = {};

    auto stage = [&](int kt, int buf) {
        const int k0 = kt << 7;
        unsigned char* Ad = As + buf * 16384;
        unsigned char* Bd = Bs + buf * 8192;
#pragma unroll
        for (int p = 0; p < 4; ++p) {
            int c = (p << 8) + tid;
            int row = c >> 3, sg = ((c & 7) ^ (row & 7)) << 4;
            async_copy16(Pb + (long)row * 4096 + k0 + sg, Ad + (c << 4));
        }
#pragma unroll
        for (int p = 0; p < 2; ++p) {
            int c = (p << 8) + tid;
            int row = c >> 3, sg = ((c & 7) ^ (row & 7)) << 4;
            async_copy16(Vb + (long)row * 4096 + k0 + sg, Bd + (c << 4));
        }
    };

    stage(0, 0);
    stage(1, 1);
    for (int ki = 0; ki < 32; ++ki) {
        if (ki < 31) ASM_VMCNT(6);
        else ASM_VMCNT(0);
        __builtin_amdgcn_s_barrier();
        const int cur = ki & 1;
        const unsigned char* Ar = As + cur * 16384;
        const unsigned char* Br = Bs + cur * 8192;
        i32x8 af[4], bf[2];
        int saw[4];
#pragma unroll
        for (int t = 0; t < 4; ++t) {
            int row = wm + t * 16 + ln, e = row & 7;
            const unsigned char* ap = Ar + (row << 7);
            *(int4*)&af[t] = *(const int4*)(ap + ((((q << 1)) ^ e) << 4));
            *((int4*)&af[t] + 1) = *(const int4*)(ap + ((((q << 1) | 1) ^ e) << 4));
            saw[t] = (int)sb_lds[(row << 5) + ki] * 0x01010101;  // byte in all lanes
        }
#pragma unroll
        for (int t = 0; t < 2; ++t) {
            int row = wn + t * 16 + ln, e = row & 7;
            const unsigned char* bp = Br + (row << 7);
            *(int4*)&bf[t] = *(const int4*)(bp + ((((q << 1)) ^ e) << 4));
            *((int4*)&bf[t] + 1) = *(const int4*)(bp + ((((q << 1) | 1) ^ e) << 4));
        }
        ASM_LGKM0();
        __builtin_amdgcn_s_barrier();
        if (ki + 2 < 32) stage(ki + 2, cur);
        __builtin_amdgcn_s_setprio(1);
#pragma unroll
        for (int mt = 0; mt < 4; ++mt)
#pragma unroll
            for (int nt = 0; nt < 2; ++nt)
                acc[mt][nt] = __builtin_amdgcn_mfma_scale_f32_16x16x128_f8f6f4(
                    af[mt], bf[nt], acc[mt][nt], 0, 0, 0, saw[mt], 0, MXSCALE);
        __builtin_amdgcn_s_setprio(0);
    }

    __bf16* Ob = O + (long)b * 4096 * 512;
#pragma unroll
    for (int mt = 0; mt < 4; ++mt) {
#pragma unroll
        for (int nt = 0; nt < 2; ++nt) {
            long col = n0 + wn + nt * 16 + ln;
#pragma unroll
            for (int r = 0; r < 4; ++r) {
                int rowl = wm + mt * 16 + (q << 2) + r;
                Ob[(m0 + rowl) * 512 + col] = (__bf16)(acc[mt][nt][r] * inv_lds[rowl]);
            }
        }
    }
}

// ---------------------------------------------------------------------------
// Proj GEMM (bf16 anchor): out = wp.o_t + bp + x. Memory-bound.
// ---------------------------------------------------------------------------
__global__ __launch_bounds__(256) void proj_kernel(
    const __bf16* __restrict__ A, const __bf16* __restrict__ Bt, long bsB,
    float* __restrict__ C, long bsC, const float* __restrict__ bias,
    const float* __restrict__ resid) {
    __shared__ __align__(16) __bf16 As[128][64];
    __shared__ __align__(16) __bf16 Bs[64][64];
    const int tid = threadIdx.x;
    const int wave = tid >> 6, lane = tid & 63;
    const int q = lane >> 4, ln = lane & 15;
    const int wm = wave << 5;
    const long m0 = (long)blockIdx.y * 128, n0 = (long)blockIdx.x * 64;
    const int b = blockIdx.z;
    const __bf16* Ab = A + m0 * 512;
    const __bf16* Bb = Bt + (long)b * bsB + n0 * 512;

    f32x4 acc[2][4] = {};

    for (int k0 = 0; k0 < 512; k0 += 64) {
        __syncthreads();
#pragma unroll
        for (int p = 0; p < 4; ++p) {
            int c = (p << 8) + tid;
            int row = c >> 3, sg = (c & 7) << 3;
            async_copy16(Ab + (long)row * 512 + k0 + sg, &As[0][0] + (c << 3));
        }
#pragma unroll
        for (int p = 0; p < 2; ++p) {
            int c = (p << 8) + tid;
            int row = c >> 3, sg = (c & 7) << 3;
            async_copy16(Bb + (long)row * 512 + k0 + sg, &Bs[0][0] + (c << 3));
        }
        __syncthreads();
#pragma unroll
        for (int kk = 0; kk < 2; ++kk) {
            bf16x8 af[2], bfr[4];
#pragma unroll
            for (int mt = 0; mt < 2; ++mt)
                af[mt] = *(const bf16x8*)(&As[wm + mt * 16 + ln][(kk << 5) + (q << 3)]);
#pragma unroll
            for (int nt = 0; nt < 4; ++nt)
                bfr[nt] = *(const bf16x8*)(&Bs[nt * 16 + ln][(kk << 5) + (q << 3)]);
#pragma unroll
            for (int mt = 0; mt < 2; ++mt)
#pragma unroll
                for (int nt = 0; nt < 4; ++nt)
                    acc[mt][nt] = __builtin_amdgcn_mfma_f32_16x16x32_bf16(
                        af[mt], bfr[nt], acc[mt][nt], 0, 0, 0);
        }
    }

#pragma unroll
    for (int mt = 0; mt < 2; ++mt) {
#pragma unroll
        for (int nt = 0; nt < 4; ++nt) {
            long col = n0 + nt * 16 + ln;
#pragma unroll
            for (int r = 0; r < 4; ++r) {
                long row = m0 + wm + mt * 16 + (q << 2) + r;
                long off = (long)b * bsC + row * 4096 + col;
                C[off] = acc[mt][nt][r] + bias[row] + resid[off];
            }
        }
    }
}

// ---------------------------------------------------------------------------
extern "C" void kernel_launch(void* const* d_in, const int* in_sizes, int n_in,
                              void* d_out, int out_size, void* d_ws, size_t ws_size,
                              hipStream_t stream) {
    const float* x = (const float*)d_in[0];
    const float* gn_scale = (const float*)d_in[1];
    const float* gn_bias = (const float*)d_in[2];
    const float* wq = (const float*)d_in[3];
    const float* bq = (const float*)d_in[4];
    const float* wk = (const float*)d_in[5];
    const float* bk = (const float*)d_in[6];
    const float* wv = (const float*)d_in[7];
    const float* bv = (const float*)d_in[8];
    const float* wp = (const float*)d_in[9];
    const float* bp = (const float*)d_in[10];
    float* out = (float*)d_out;

    char* ws = (char*)d_ws;
    unsigned char* wqk8 = (unsigned char*)(ws + 0x0);      // [1024][512] fp8
    unsigned char* wv8 = (unsigned char*)(ws + 0x80000);   // [512][512] fp8
    __bf16* wp_b = (__bf16*)(ws + 0xC0000);                // [512][512] bf16
    float* bqk = (float*)(ws + 0x140000);                  // [1024] f32
    float* psum = (float*)(ws + 0x142000);                 // [2][1024] f32
    unsigned char* hn8 = (unsigned char*)(ws + 0x150000);  // [2][4096][512] fp8, 4 MB
    unsigned char* qk8 = (unsigned char*)(ws + 0x550000);  // [2][4096][1024] fp8, 8 MB
    unsigned char* v8 = (unsigned char*)(ws + 0xD50000);   // [2][512][4096] fp8, 4 MB
    __bf16* o_t = (__bf16*)(ws + 0x1150000);               // [2][4096][512] bf16, 8 MB
    unsigned char* S8 = (unsigned char*)(ws + 0x1950000);  // [2][4096][4096] fp8 P', 32 MB
    float* pmaxF = (float*)(ws + 0x3950000);               // [8192][32] f32, 1 MB
    float* psumF = (float*)(ws + 0x3A50000);               // [8192][32] f32, 1 MB
    (void)ws_size;  // ~61 MB footprint

    prep_kernel<<<2048, 256, 0, stream>>>(x, psum, wq, wk, wv, wp, bq, bk,
                                          wqk8, wv8, wp_b, bqk);
    gn_apply_kernel<<<dim3(128, 16, 2), 256, 0, stream>>>(x, gn_scale, gn_bias,
                                                          psum, hn8);
    qkv_kernel<<<dim3(8, 32, 4), 256, 0, stream>>>(hn8, wqk8, wv8, bqk, bv,
                                                   qk8, v8);

    const float attn_scale = 0.044194173824159216f;  // 512^-0.5
    // St = K.Q^T + per-panel softmax partials (2048 blocks, XCD-chunked)
    mx_s_softmax_kernel<<<2048, 256, 0, stream>>>(qk8, S8, pmaxF, psumF,
                                                  attn_scale);
    // PV with e8m0 row-block scales + 1/denom epilogue (512 blocks)
    mx_pv_scaled_kernel<<<dim3(64, 8), 256, 0, stream>>>(S8, v8, pmaxF, psumF,
                                                         o_t);

    proj_kernel<<<dim3(64, 4, 2), 256, 0, stream>>>(
        wp_b, o_t, 4096l * 512, out, 512l * 4096, bp, x);
}